// Round 7
// baseline (363.350 us; speedup 1.0000x reference)
//
#include <hip/hip_runtime.h>

#define N_NODES   100000
#define N_EDGES   3200000
#define F_INP     128
#define HID       64
#define N_GRAPHS  512
#define N_CLASSES 2
#define BSH       8                        // bucket shift: 256 target nodes per bucket
#define BSZ       256
#define NB        391                      // ceil(N/256) buckets
#define SCAT_BLOCKS 1024                   // 4 blocks/CU -> 4 waves/SIMD latency hiding
#define CHUNK     (N_EDGES / SCAT_BLOCKS)  // 3125, exact
#define CAP2      8960                     // per-bucket region: mean 8184, sigma 90 -> +8.6 sigma

// bf16 helpers: RTN encode; decode low/high halves of a packed u32
__device__ __forceinline__ unsigned short f2bf(float f) {
    unsigned int u = __float_as_uint(f);
    return (unsigned short)((u + 0x7FFFu + ((u >> 16) & 1u)) >> 16);
}
__device__ __forceinline__ float bf_lo(unsigned int u) { return __uint_as_float(u << 16); }
__device__ __forceinline__ float bf_hi(unsigned int u) { return __uint_as_float(u & 0xFFFF0000u); }

// ---------- pass 1 (fused): LDS count -> global range reserve -> place ----------
// pairs[b*CAP2 + pos] = r | (local_c << 17); gcur[b] accumulates true bucket totals.
__global__ __launch_bounds__(256) void scatterX(const int* __restrict__ ei,
                                                int* __restrict__ gcur,
                                                int* __restrict__ pairs) {
    __shared__ int lcnt[NB];
    __shared__ int lbase[NB];
    __shared__ int lcur[NB];
    const int tid = threadIdx.x;
    for (int i = tid; i < NB; i += 256) { lcnt[i] = 0; lcur[i] = 0; }
    __syncthreads();
    const int e0 = blockIdx.x * CHUNK;
    for (int e = e0 + tid; e < e0 + CHUNK; e += 256)
        atomicAdd(&lcnt[ei[N_EDGES + e] >> BSH], 1);
    __syncthreads();
    for (int i = tid; i < NB; i += 256) {
        int c = lcnt[i];
        lbase[i] = c ? atomicAdd(&gcur[i], c) : 0;   // reserve disjoint range in bucket region
    }
    __syncthreads();
    for (int e = e0 + tid; e < e0 + CHUNK; e += 256) {
        int c = ei[N_EDGES + e];
        int r = ei[e];
        int b = c >> BSH;
        int off = atomicAdd(&lcur[b], 1);
        int pos = lbase[b] + off;
        if (pos < CAP2)                               // ~8.6-sigma guard
            pairs[b * CAP2 + pos] = r | ((c & (BSZ - 1)) << 17);
    }
}

// ---------- pass 2: exclusive scan of bucket totals -> compact boff ----------
__global__ __launch_bounds__(512) void bscan_kernel(const int* __restrict__ gcur,
                                                    int* __restrict__ boff,
                                                    int* __restrict__ offs) {
    __shared__ int s[512];
    const int tid = threadIdx.x;
    const int v = (tid < NB) ? min(gcur[tid], CAP2) : 0;
    s[tid] = v;
    __syncthreads();
    for (int d = 1; d < 512; d <<= 1) {
        int t = (tid >= d) ? s[tid - d] : 0;
        __syncthreads();
        s[tid] += t;
        __syncthreads();
    }
    if (tid <= NB) boff[tid] = s[tid] - v;   // exclusive; tid==NB -> grand total
    if (tid == NB) offs[N_NODES] = s[tid];   // == N_EDGES barring ~1e-17 drop
}

// ---------- pass 3: per-bucket CSR build, input staged in LDS once (8 waves/block) ----------
__global__ __launch_bounds__(512) void csrX(const int* __restrict__ pairs,
                                            const int* __restrict__ gcur,
                                            const int* __restrict__ boff,
                                            int* __restrict__ adj,
                                            int* __restrict__ offs,
                                            float* __restrict__ dis) {
    __shared__ int sedge[CAP2];   // 35.8 KB
    __shared__ int cnt[BSZ];
    __shared__ int sc[BSZ];
    __shared__ int base[BSZ];
    __shared__ int cur[BSZ];
    const int tid = threadIdx.x;
    const int b = blockIdx.x;
    const int m = min(gcur[b], CAP2);
    const int dst = boff[b];
    if (tid < BSZ) { cnt[tid] = 0; cur[tid] = 0; }
    __syncthreads();
    for (int i = tid; i < m; i += 512) {        // coalesced read, stage, count
        int v = pairs[b * CAP2 + i];
        sedge[i] = v;
        atomicAdd(&cnt[v >> 17], 1);
    }
    __syncthreads();
    if (tid < BSZ) sc[tid] = cnt[tid];
    __syncthreads();
    for (int d = 1; d < BSZ; d <<= 1) {
        int t = (tid >= d && tid < BSZ) ? sc[tid - d] : 0;
        __syncthreads();
        if (tid < BSZ) sc[tid] += t;
        __syncthreads();
    }
    if (tid < BSZ) base[tid] = dst + sc[tid] - cnt[tid];   // exclusive + bucket base
    __syncthreads();
    for (int i = tid; i < m; i += 512) {        // place from LDS
        int v = sedge[i];
        int lc = v >> 17;
        int o = atomicAdd(&cur[lc], 1);
        adj[base[lc] + o] = v & 131071;
    }
    const int n = (b << BSH) + tid;
    if (tid < BSZ && n < N_NODES) {
        offs[n] = base[tid];
        dis[n] = rsqrtf((float)cnt[tid] + 1.0f);           // +1 = self-loop
    }
}

// ---------- mm1: p = bf16(dis * (x @ W1)), 32-row LDS tile, padded (no bank conflicts) ----------
#define MM1_ROWS 32
#define XS_LD    132                       // 128 + 4 pad floats -> bank shift 4/row
__global__ __launch_bounds__(256) void mm1_kernel(const float* __restrict__ x,
                                                  const float* __restrict__ W1,
                                                  const float* __restrict__ dis,
                                                  unsigned short* __restrict__ p) {
    __shared__ float xs[MM1_ROWS * XS_LD]; // 16.9 KB
    __shared__ float ws[F_INP * HID];      // 32 KB
    for (int i = threadIdx.x; i < F_INP * HID / 4; i += 256)
        ((float4*)ws)[i] = ((const float4*)W1)[i];
    const int row_base = blockIdx.x * MM1_ROWS;
    for (int i = threadIdx.x; i < MM1_ROWS * (F_INP / 4); i += 256) {
        int r = i >> 5, c4 = i & 31;
        int gr = row_base + r;
        float4 v = make_float4(0.f, 0.f, 0.f, 0.f);
        if (gr < N_NODES) v = *(const float4*)(x + (size_t)gr * F_INP + c4 * 4);
        *(float4*)(xs + r * XS_LD + c4 * 4) = v;
    }
    __syncthreads();
    const int tx = threadIdx.x & 15;
    const int ty = threadIdx.x >> 4;
    float acc[2][4] = {};
#pragma unroll 4
    for (int k = 0; k < F_INP; k += 4) {
        float4 a0 = *(const float4*)(xs + ty * XS_LD + k);
        float4 a1 = *(const float4*)(xs + (ty + 16) * XS_LD + k);
        float4 w0 = *(const float4*)(ws + (k + 0) * HID + tx * 4);
        float4 w1 = *(const float4*)(ws + (k + 1) * HID + tx * 4);
        float4 w2 = *(const float4*)(ws + (k + 2) * HID + tx * 4);
        float4 w3 = *(const float4*)(ws + (k + 3) * HID + tx * 4);
        acc[0][0] += a0.x * w0.x + a0.y * w1.x + a0.z * w2.x + a0.w * w3.x;
        acc[0][1] += a0.x * w0.y + a0.y * w1.y + a0.z * w2.y + a0.w * w3.y;
        acc[0][2] += a0.x * w0.z + a0.y * w1.z + a0.z * w2.z + a0.w * w3.z;
        acc[0][3] += a0.x * w0.w + a0.y * w1.w + a0.z * w2.w + a0.w * w3.w;
        acc[1][0] += a1.x * w0.x + a1.y * w1.x + a1.z * w2.x + a1.w * w3.x;
        acc[1][1] += a1.x * w0.y + a1.y * w1.y + a1.z * w2.y + a1.w * w3.y;
        acc[1][2] += a1.x * w0.z + a1.y * w1.z + a1.z * w2.z + a1.w * w3.z;
        acc[1][3] += a1.x * w0.w + a1.y * w1.w + a1.z * w2.w + a1.w * w3.w;
    }
#pragma unroll
    for (int i = 0; i < 2; ++i) {
        int rr = row_base + ty + 16 * i;
        if (rr < N_NODES) {
            float d = dis[rr];
            ushort4 o;
            o.x = f2bf(d * acc[i][0]);
            o.y = f2bf(d * acc[i][1]);
            o.z = f2bf(d * acc[i][2]);
            o.w = f2bf(d * acc[i][3]);
            *(ushort4*)(p + (size_t)rr * HID + tx * 4) = o;
        }
    }
}

// ---------- mm2: p = bf16(dis * (h @ W2)), 64-row bf16 tile, padded ----------
#define HS_LD 72                            // 64 + 8 pad bf16 -> 144 B/row, bank shift 4
__global__ __launch_bounds__(256) void mm2_kernel(const unsigned short* __restrict__ hb,
                                                  const float* __restrict__ W2,
                                                  const float* __restrict__ dis,
                                                  unsigned short* __restrict__ p) {
    __shared__ unsigned short hs[64 * HS_LD];  // 9.2 KB
    __shared__ float ws[HID * HID];            // 16 KB
    for (int i = threadIdx.x; i < HID * HID / 4; i += 256)
        ((float4*)ws)[i] = ((const float4*)W2)[i];
    const int row_base = blockIdx.x * 64;
    for (int i = threadIdx.x; i < 64 * (HID / 8); i += 256) {
        int r = i >> 3, c8 = i & 7;
        int gr = row_base + r;
        uint4 v = make_uint4(0u, 0u, 0u, 0u);
        if (gr < N_NODES) v = *(const uint4*)(hb + (size_t)gr * HID + c8 * 8);
        *(uint4*)(hs + r * HS_LD + c8 * 8) = v;
    }
    __syncthreads();
    const int tx = threadIdx.x & 15;
    const int ty = threadIdx.x >> 4;
    float acc[4][4] = {};
#pragma unroll 2
    for (int k = 0; k < HID; k += 8) {
        uint4 a[4];
#pragma unroll
        for (int i = 0; i < 4; ++i)
            a[i] = *(const uint4*)(hs + (ty + 16 * i) * HS_LD + k);
        float4 w[8];
#pragma unroll
        for (int m = 0; m < 8; ++m)
            w[m] = *(const float4*)(ws + (k + m) * HID + tx * 4);
#pragma unroll
        for (int i = 0; i < 4; ++i) {
            float h0 = bf_lo(a[i].x), h1 = bf_hi(a[i].x);
            float h2 = bf_lo(a[i].y), h3 = bf_hi(a[i].y);
            float h4 = bf_lo(a[i].z), h5 = bf_hi(a[i].z);
            float h6 = bf_lo(a[i].w), h7 = bf_hi(a[i].w);
            acc[i][0] += h0 * w[0].x + h1 * w[1].x + h2 * w[2].x + h3 * w[3].x
                       + h4 * w[4].x + h5 * w[5].x + h6 * w[6].x + h7 * w[7].x;
            acc[i][1] += h0 * w[0].y + h1 * w[1].y + h2 * w[2].y + h3 * w[3].y
                       + h4 * w[4].y + h5 * w[5].y + h6 * w[6].y + h7 * w[7].y;
            acc[i][2] += h0 * w[0].z + h1 * w[1].z + h2 * w[2].z + h3 * w[3].z
                       + h4 * w[4].z + h5 * w[5].z + h6 * w[6].z + h7 * w[7].z;
            acc[i][3] += h0 * w[0].w + h1 * w[1].w + h2 * w[2].w + h3 * w[3].w
                       + h4 * w[4].w + h5 * w[5].w + h6 * w[6].w + h7 * w[7].w;
        }
    }
#pragma unroll
    for (int i = 0; i < 4; ++i) {
        int rr = row_base + ty + 16 * i;
        if (rr < N_NODES) {
            float d = dis[rr];
            ushort4 o;
            o.x = f2bf(d * acc[i][0]);
            o.y = f2bf(d * acc[i][1]);
            o.z = f2bf(d * acc[i][2]);
            o.w = f2bf(d * acc[i][3]);
            *(ushort4*)(p + (size_t)rr * HID + tx * 4) = o;
        }
    }
}

// ---------- round-8 gather core (empirical optimum): 32/16/masked-8 loops ----------
// lane L: q = L>>3 (row slot), g = L&7 (feature octet, feats 8g..8g+7)
__device__ __forceinline__ float gather_node(const unsigned short* __restrict__ p,
                                             const int* __restrict__ adj,
                                             int c, int beg, int end, int q, int g) {
    float acc[8];
    {   // self-loop row, counted once via q==0 lanes
        uint4 s = *(const uint4*)(p + (size_t)c * HID + g * 8);
        float sm = (q == 0) ? 1.f : 0.f;
        acc[0] = sm * bf_lo(s.x); acc[1] = sm * bf_hi(s.x);
        acc[2] = sm * bf_lo(s.y); acc[3] = sm * bf_hi(s.y);
        acc[4] = sm * bf_lo(s.z); acc[5] = sm * bf_hi(s.z);
        acc[6] = sm * bf_lo(s.w); acc[7] = sm * bf_hi(s.w);
    }
    int e = beg;
    for (; e + 32 <= end; e += 32) {            // 4 row-loads in flight
        int r0 = adj[e + q];
        int r1 = adj[e + 8 + q];
        int r2 = adj[e + 16 + q];
        int r3 = adj[e + 24 + q];
        uint4 v0 = *(const uint4*)(p + (size_t)r0 * HID + g * 8);
        uint4 v1 = *(const uint4*)(p + (size_t)r1 * HID + g * 8);
        uint4 v2 = *(const uint4*)(p + (size_t)r2 * HID + g * 8);
        uint4 v3 = *(const uint4*)(p + (size_t)r3 * HID + g * 8);
        acc[0] += (bf_lo(v0.x) + bf_lo(v1.x)) + (bf_lo(v2.x) + bf_lo(v3.x));
        acc[1] += (bf_hi(v0.x) + bf_hi(v1.x)) + (bf_hi(v2.x) + bf_hi(v3.x));
        acc[2] += (bf_lo(v0.y) + bf_lo(v1.y)) + (bf_lo(v2.y) + bf_lo(v3.y));
        acc[3] += (bf_hi(v0.y) + bf_hi(v1.y)) + (bf_hi(v2.y) + bf_hi(v3.y));
        acc[4] += (bf_lo(v0.z) + bf_lo(v1.z)) + (bf_lo(v2.z) + bf_lo(v3.z));
        acc[5] += (bf_hi(v0.z) + bf_hi(v1.z)) + (bf_hi(v2.z) + bf_hi(v3.z));
        acc[6] += (bf_lo(v0.w) + bf_lo(v1.w)) + (bf_lo(v2.w) + bf_lo(v3.w));
        acc[7] += (bf_hi(v0.w) + bf_hi(v1.w)) + (bf_hi(v2.w) + bf_hi(v3.w));
    }
    for (; e + 16 <= end; e += 16) {
        int r0 = adj[e + q];
        int r1 = adj[e + 8 + q];
        uint4 v0 = *(const uint4*)(p + (size_t)r0 * HID + g * 8);
        uint4 v1 = *(const uint4*)(p + (size_t)r1 * HID + g * 8);
        acc[0] += bf_lo(v0.x) + bf_lo(v1.x); acc[1] += bf_hi(v0.x) + bf_hi(v1.x);
        acc[2] += bf_lo(v0.y) + bf_lo(v1.y); acc[3] += bf_hi(v0.y) + bf_hi(v1.y);
        acc[4] += bf_lo(v0.z) + bf_lo(v1.z); acc[5] += bf_hi(v0.z) + bf_hi(v1.z);
        acc[6] += bf_lo(v0.w) + bf_lo(v1.w); acc[7] += bf_hi(v0.w) + bf_hi(v1.w);
    }
    for (; e < end; e += 8) {                   // masked tail
        int idx = e + q;
        int r = adj[min(idx, end - 1)];
        float m = (idx < end) ? 1.f : 0.f;
        uint4 v = *(const uint4*)(p + (size_t)r * HID + g * 8);
        acc[0] = fmaf(m, bf_lo(v.x), acc[0]); acc[1] = fmaf(m, bf_hi(v.x), acc[1]);
        acc[2] = fmaf(m, bf_lo(v.y), acc[2]); acc[3] = fmaf(m, bf_hi(v.y), acc[3]);
        acc[4] = fmaf(m, bf_lo(v.z), acc[4]); acc[5] = fmaf(m, bf_hi(v.z), acc[5]);
        acc[6] = fmaf(m, bf_lo(v.w), acc[6]); acc[7] = fmaf(m, bf_hi(v.w), acc[7]);
    }
    // select-tree reduction over q bits (lane ends with feature 8g+q)
    const bool q0 = (q & 1) != 0, q1 = (q & 2) != 0, q2 = (q & 4) != 0;
    float b0 = (q0 ? acc[1] : acc[0]) + __shfl_xor(q0 ? acc[0] : acc[1], 8, 64);
    float b1 = (q0 ? acc[3] : acc[2]) + __shfl_xor(q0 ? acc[2] : acc[3], 8, 64);
    float b2 = (q0 ? acc[5] : acc[4]) + __shfl_xor(q0 ? acc[4] : acc[5], 8, 64);
    float b3 = (q0 ? acc[7] : acc[6]) + __shfl_xor(q0 ? acc[6] : acc[7], 8, 64);
    float c0 = (q1 ? b1 : b0) + __shfl_xor(q1 ? b0 : b1, 16, 64);
    float c1 = (q1 ? b3 : b2) + __shfl_xor(q1 ? b2 : b3, 16, 64);
    return (q2 ? c1 : c0) + __shfl_xor(q2 ? c0 : c1, 32, 64);
}

// ---------- gather1: hb = bf16(relu(dis[c]*(p[c]+sum p[r]) + b1)), contiguous chunks ----------
__global__ __launch_bounds__(256) void gather1_kernel(const unsigned short* __restrict__ p,
                                                      const int* __restrict__ adj,
                                                      const int* __restrict__ offs,
                                                      const float* __restrict__ dis,
                                                      const float* __restrict__ b1,
                                                      unsigned short* __restrict__ hb) {
    const int lane = threadIdx.x & 63;
    const int q = lane >> 3, g = lane & 7;
    const int gwave = (blockIdx.x * blockDim.x + threadIdx.x) >> 6;
    const int nwaves = (gridDim.x * blockDim.x) >> 6;
    const int per = (N_NODES + nwaves - 1) / nwaves;
    const int c0 = gwave * per;
    const int c1 = min(N_NODES, c0 + per);
    const float bj = b1[g * 8 + q];
    if (c0 >= c1) return;
    int beg = offs[c0];                       // carry offs[c+1] -> next beg
    for (int c = c0; c < c1; ++c) {
        const int end = offs[c + 1];
        float val = gather_node(p, adj, c, beg, end, q, g);
        hb[(size_t)c * HID + g * 8 + q] = f2bf(fmaxf(dis[c] * val + bj, 0.f));
        beg = end;
    }
}

// ---------- gather2 + mean-pool numerator (run-length atomics over sorted batch) ----------
__global__ __launch_bounds__(256) void gather2_kernel(const unsigned short* __restrict__ p,
                                                      const int* __restrict__ adj,
                                                      const int* __restrict__ offs,
                                                      const float* __restrict__ dis,
                                                      const float* __restrict__ b2,
                                                      const int* __restrict__ batch,
                                                      float* __restrict__ sums) {
    const int lane = threadIdx.x & 63;
    const int q = lane >> 3, g = lane & 7;
    const int gwave = (blockIdx.x * blockDim.x + threadIdx.x) >> 6;
    const int nwaves = (gridDim.x * blockDim.x) >> 6;
    const int per = (N_NODES + nwaves - 1) / nwaves;
    const int c0 = gwave * per;
    const int c1 = min(N_NODES, c0 + per);
    const float bj = b2[g * 8 + q];
    const int feat = g * 8 + q;
    float part = 0.f;
    int gc = -1;
    if (c0 >= c1) return;
    int beg = offs[c0];                       // carry offs[c+1] -> next beg
    for (int c = c0; c < c1; ++c) {
        const int end = offs[c + 1];
        float val = gather_node(p, adj, c, beg, end, q, g);
        float v = fmaxf(dis[c] * val + bj, 0.f);
        int gid = batch[c];                       // wave-uniform
        if (gid != gc) {
            if (gc >= 0) atomicAdd(&sums[(size_t)gc * HID + feat], part);
            part = 0.f;
            gc = gid;
        }
        part += v;
        beg = end;
    }
    if (gc >= 0) atomicAdd(&sums[(size_t)gc * HID + feat], part);
}

// ---------- final FC (counts fused via binary search on sorted batch) ----------
__global__ void fc_kernel(const float* __restrict__ sums, const int* __restrict__ batch,
                          const float* __restrict__ Wfc, const float* __restrict__ bfc,
                          float* __restrict__ out) {
    const int g = blockIdx.x;
    const int j = threadIdx.x;
    int lo = 0, hi = N_NODES;
    while (lo < hi) { int m = (lo + hi) >> 1; if (batch[m] < g) lo = m + 1; else hi = m; }
    const int l0 = lo;
    lo = 0; hi = N_NODES;
    while (lo < hi) { int m = (lo + hi) >> 1; if (batch[m] < g + 1) lo = m + 1; else hi = m; }
    float cnt = fmaxf((float)(lo - l0), 1.0f);
    float pj = sums[(size_t)g * HID + j] / cnt;
    float a0 = pj * Wfc[j * N_CLASSES + 0];
    float a1 = pj * Wfc[j * N_CLASSES + 1];
    for (int off = 32; off > 0; off >>= 1) {
        a0 += __shfl_down(a0, off, 64);
        a1 += __shfl_down(a1, off, 64);
    }
    if (j == 0) {
        out[g * N_CLASSES + 0] = a0 + bfc[0];
        out[g * N_CLASSES + 1] = a1 + bfc[1];
    }
}

extern "C" void kernel_launch(void* const* d_in, const int* in_sizes, int n_in,
                              void* d_out, int out_size, void* d_ws, size_t ws_size,
                              hipStream_t stream) {
    const float* x     = (const float*)d_in[0];
    const int*   ei    = (const int*)d_in[1];   // [2,E]: row=ei[0:E], col=ei[E:2E]
    const int*   batch = (const int*)d_in[2];
    const float* W1    = (const float*)d_in[3];
    const float* b1    = (const float*)d_in[4];
    const float* W2    = (const float*)d_in[5];
    const float* b2    = (const float*)d_in[6];
    const float* Wfc   = (const float*)d_in[7];
    const float* bfc   = (const float*)d_in[8];
    float* out = (float*)d_out;

    char* ws = (char*)d_ws;
    size_t off = 0;
    auto alloc = [&](size_t bytes) -> void* {
        void* pp = ws + off;
        off += (bytes + 255) & ~(size_t)255;
        return pp;
    };
    // gcur and sums adjacent -> single memset covers both
    int*   gcur   = (int*)alloc((size_t)NB * 4);                      // 1.6 KB (pads to 1792B)
    float* sums   = (float*)alloc((size_t)N_GRAPHS * HID * 4);        // 128 KB
    int*   boff   = (int*)alloc((size_t)(NB + 1) * 4);
    int*   offs   = (int*)alloc((size_t)(N_NODES + 1) * 4);
    float* dis    = (float*)alloc((size_t)N_NODES * 4);
    int*   pairs  = (int*)alloc((size_t)NB * CAP2 * 4);               // 14.0 MB
    int*   adj    = (int*)alloc((size_t)N_EDGES * 4);
    unsigned short* p  = (unsigned short*)alloc((size_t)N_NODES * HID * 2);
    unsigned short* hb = (unsigned short*)alloc((size_t)N_NODES * HID * 2);

    hipMemsetAsync(gcur, 0, (size_t)((char*)(sums + N_GRAPHS * HID) - (char*)gcur), stream);

    scatterX<<<SCAT_BLOCKS, 256, 0, stream>>>(ei, gcur, pairs);
    bscan_kernel<<<1, 512, 0, stream>>>(gcur, boff, offs);
    csrX<<<NB, 512, 0, stream>>>(pairs, gcur, boff, adj, offs, dis);
    mm1_kernel<<<(N_NODES + MM1_ROWS - 1) / MM1_ROWS, 256, 0, stream>>>(x, W1, dis, p);
    gather1_kernel<<<2048, 256, 0, stream>>>(p, adj, offs, dis, b1, hb);
    mm2_kernel<<<(N_NODES + 63) / 64, 256, 0, stream>>>(hb, W2, dis, p);
    gather2_kernel<<<2048, 256, 0, stream>>>(p, adj, offs, dis, b2, batch, sums);
    fc_kernel<<<N_GRAPHS, 64, 0, stream>>>(sums, batch, Wfc, bfc, out);
}

// Round 8
// 348.186 us; speedup vs baseline: 1.0435x; 1.0435x over previous
//
#include <hip/hip_runtime.h>

#define N_NODES   100000
#define N_EDGES   3200000
#define F_INP     128
#define HID       64
#define N_GRAPHS  512
#define N_CLASSES 2
#define BSH       8                        // bucket shift: 256 target nodes per bucket
#define BSZ       256
#define NB        391                      // ceil(N/256) buckets
#define SCAT_BLOCKS 256                    // proven optimum (R7: more blocks -> shorter runs -> slower)
#define CHUNK     (N_EDGES / SCAT_BLOCKS)  // 12500, exact
#define CAP2      8960                     // per-bucket region: mean 8184, sigma 90 -> +8.6 sigma
#define MM1_ROWS  32
#define XS_LD     132                      // 128 + 4 pad floats -> bank shift 4/row
#define MM1_BLOCKS ((N_NODES + MM1_ROWS - 1) / MM1_ROWS)   // 3125

// bf16 helpers: RTN encode; decode low/high halves of a packed u32
__device__ __forceinline__ unsigned short f2bf(float f) {
    unsigned int u = __float_as_uint(f);
    return (unsigned short)((u + 0x7FFFu + ((u >> 16) & 1u)) >> 16);
}
__device__ __forceinline__ float bf_lo(unsigned int u) { return __uint_as_float(u << 16); }
__device__ __forceinline__ float bf_hi(unsigned int u) { return __uint_as_float(u & 0xFFFF0000u); }

// ---------- pass 1 (mega-fused): blocks [0,256) scatter edges; blocks [256,3381) do x@W1 ----------
// Scatter is store-miss-latency-bound with idle VALU; mm1 is VALU/LDS-bound -> co-residency
// hides mm1's ~18us under the scatter floor. mm1 writes UNSCALED f32 praw (dis not known yet;
// f32 keeps single-rounding precision; csrX applies dis and converts to bf16).
__global__ __launch_bounds__(256) void fused_pre(const int* __restrict__ ei,
                                                 int* __restrict__ gcur,
                                                 int* __restrict__ pairs,
                                                 const float* __restrict__ x,
                                                 const float* __restrict__ W1,
                                                 float* __restrict__ praw) {
    __shared__ __align__(16) char smem[(MM1_ROWS * XS_LD + F_INP * HID) * 4];  // 49.7 KB union
    const int tid = threadIdx.x;
    if (blockIdx.x < SCAT_BLOCKS) {
        // ---- scatter part (identical to round-6 scatterX) ----
        int* lcnt = (int*)smem;
        int* lbase = lcnt + NB;
        int* lcur = lbase + NB;
        for (int i = tid; i < NB; i += 256) { lcnt[i] = 0; lcur[i] = 0; }
        __syncthreads();
        const int e0 = blockIdx.x * CHUNK;
        for (int e = e0 + tid; e < e0 + CHUNK; e += 256)
            atomicAdd(&lcnt[ei[N_EDGES + e] >> BSH], 1);
        __syncthreads();
        for (int i = tid; i < NB; i += 256) {
            int c = lcnt[i];
            lbase[i] = c ? atomicAdd(&gcur[i], c) : 0;   // reserve disjoint range
        }
        __syncthreads();
        for (int e = e0 + tid; e < e0 + CHUNK; e += 256) {
            int c = ei[N_EDGES + e];
            int r = ei[e];
            int b = c >> BSH;
            int off = atomicAdd(&lcur[b], 1);
            int pos = lbase[b] + off;
            if (pos < CAP2)                               // ~8.6-sigma guard
                pairs[b * CAP2 + pos] = r | ((c & (BSZ - 1)) << 17);
        }
    } else {
        // ---- mm1 part: praw = x @ W1 (f32, unscaled) ----
        float* xs = (float*)smem;
        float* ws = xs + MM1_ROWS * XS_LD;
        for (int i = tid; i < F_INP * HID / 4; i += 256)
            ((float4*)ws)[i] = ((const float4*)W1)[i];
        const int row_base = (blockIdx.x - SCAT_BLOCKS) * MM1_ROWS;
        for (int i = tid; i < MM1_ROWS * (F_INP / 4); i += 256) {
            int r = i >> 5, c4 = i & 31;
            int gr = row_base + r;
            float4 v = make_float4(0.f, 0.f, 0.f, 0.f);
            if (gr < N_NODES) v = *(const float4*)(x + (size_t)gr * F_INP + c4 * 4);
            *(float4*)(xs + r * XS_LD + c4 * 4) = v;
        }
        __syncthreads();
        const int tx = tid & 15;
        const int ty = tid >> 4;
        float acc[2][4] = {};
#pragma unroll 4
        for (int k = 0; k < F_INP; k += 4) {
            float4 a0 = *(const float4*)(xs + ty * XS_LD + k);
            float4 a1 = *(const float4*)(xs + (ty + 16) * XS_LD + k);
            float4 w0 = *(const float4*)(ws + (k + 0) * HID + tx * 4);
            float4 w1 = *(const float4*)(ws + (k + 1) * HID + tx * 4);
            float4 w2 = *(const float4*)(ws + (k + 2) * HID + tx * 4);
            float4 w3 = *(const float4*)(ws + (k + 3) * HID + tx * 4);
            acc[0][0] += a0.x * w0.x + a0.y * w1.x + a0.z * w2.x + a0.w * w3.x;
            acc[0][1] += a0.x * w0.y + a0.y * w1.y + a0.z * w2.y + a0.w * w3.y;
            acc[0][2] += a0.x * w0.z + a0.y * w1.z + a0.z * w2.z + a0.w * w3.z;
            acc[0][3] += a0.x * w0.w + a0.y * w1.w + a0.z * w2.w + a0.w * w3.w;
            acc[1][0] += a1.x * w0.x + a1.y * w1.x + a1.z * w2.x + a1.w * w3.x;
            acc[1][1] += a1.x * w0.y + a1.y * w1.y + a1.z * w2.y + a1.w * w3.y;
            acc[1][2] += a1.x * w0.z + a1.y * w1.z + a1.z * w2.z + a1.w * w3.z;
            acc[1][3] += a1.x * w0.w + a1.y * w1.w + a1.z * w2.w + a1.w * w3.w;
        }
#pragma unroll
        for (int i = 0; i < 2; ++i) {
            int rr = row_base + ty + 16 * i;
            if (rr < N_NODES)
                *(float4*)(praw + (size_t)rr * HID + tx * 4) =
                    make_float4(acc[i][0], acc[i][1], acc[i][2], acc[i][3]);
        }
    }
}

// ---------- pass 2: per-bucket CSR build + inlined bucket-scan + dis-scale praw->p ----------
__global__ __launch_bounds__(512) void csrX(const int* __restrict__ pairs,
                                            const int* __restrict__ gcur,
                                            const float* __restrict__ praw,
                                            unsigned short* __restrict__ p,
                                            int* __restrict__ adj,
                                            int* __restrict__ offs,
                                            float* __restrict__ dis) {
    __shared__ int sedge[CAP2];   // 35.8 KB
    __shared__ int gs[512];       // inclusive scan of bucket totals (replaces bscan kernel)
    __shared__ int cnt[BSZ];
    __shared__ int sc[BSZ];
    __shared__ int base[BSZ];
    __shared__ int cur[BSZ];
    const int tid = threadIdx.x;
    const int b = blockIdx.x;
    // --- bucket-total scan (redundant per block; ~10 barriers, cheap) ---
    gs[tid] = (tid < NB) ? min(gcur[tid], CAP2) : 0;
    __syncthreads();
    for (int d = 1; d < 512; d <<= 1) {
        int t = (tid >= d) ? gs[tid - d] : 0;
        __syncthreads();
        gs[tid] += t;
        __syncthreads();
    }
    const int vb = min(gcur[b], CAP2);
    const int dst = gs[b] - vb;                 // exclusive prefix = bucket base
    const int m = vb;
    if (b == 0 && tid == 0) offs[N_NODES] = gs[511];   // grand total (== N_EDGES barring ~1e-17 drop)
    if (tid < BSZ) { cnt[tid] = 0; cur[tid] = 0; }
    __syncthreads();
    for (int i = tid; i < m; i += 512) {        // coalesced read, stage, count
        int v = pairs[b * CAP2 + i];
        sedge[i] = v;
        atomicAdd(&cnt[v >> 17], 1);
    }
    __syncthreads();
    if (tid < BSZ) sc[tid] = cnt[tid];
    __syncthreads();
    for (int d = 1; d < BSZ; d <<= 1) {
        int t = (tid >= d && tid < BSZ) ? sc[tid - d] : 0;
        __syncthreads();
        if (tid < BSZ) sc[tid] += t;
        __syncthreads();
    }
    if (tid < BSZ) base[tid] = dst + sc[tid] - cnt[tid];   // exclusive + bucket base
    __syncthreads();
    for (int i = tid; i < m; i += 512) {        // place from LDS
        int v = sedge[i];
        int lc = v >> 17;
        int o = atomicAdd(&cur[lc], 1);
        adj[base[lc] + o] = v & 131071;
    }
    const int n = (b << BSH) + tid;
    if (tid < BSZ && n < N_NODES) {
        offs[n] = base[tid];
        dis[n] = rsqrtf((float)cnt[tid] + 1.0f);           // +1 = self-loop
    }
    // --- dis-scale this bucket's praw rows (f32) into p (bf16), single rounding ---
    const int nrows = min(BSZ, N_NODES - (b << BSH));
    const float2* pr = (const float2*)(praw + ((size_t)(b << BSH)) * HID);
    unsigned int* p32 = (unsigned int*)(p + ((size_t)(b << BSH)) * HID);
    for (int i = tid; i < nrows * 32; i += 512) {
        int row = i >> 5;
        float d = rsqrtf((float)cnt[row] + 1.0f);
        float2 w = pr[i];
        p32[i] = (unsigned int)f2bf(w.x * d) | ((unsigned int)f2bf(w.y * d) << 16);
    }
}

// ---------- mm2: p = bf16(dis * (h @ W2)), 64-row bf16 tile, padded ----------
#define HS_LD 72                            // 64 + 8 pad bf16 -> 144 B/row, bank shift 4
__global__ __launch_bounds__(256) void mm2_kernel(const unsigned short* __restrict__ hb,
                                                  const float* __restrict__ W2,
                                                  const float* __restrict__ dis,
                                                  unsigned short* __restrict__ p) {
    __shared__ unsigned short hs[64 * HS_LD];  // 9.2 KB
    __shared__ float ws[HID * HID];            // 16 KB
    for (int i = threadIdx.x; i < HID * HID / 4; i += 256)
        ((float4*)ws)[i] = ((const float4*)W2)[i];
    const int row_base = blockIdx.x * 64;
    for (int i = threadIdx.x; i < 64 * (HID / 8); i += 256) {
        int r = i >> 3, c8 = i & 7;
        int gr = row_base + r;
        uint4 v = make_uint4(0u, 0u, 0u, 0u);
        if (gr < N_NODES) v = *(const uint4*)(hb + (size_t)gr * HID + c8 * 8);
        *(uint4*)(hs + r * HS_LD + c8 * 8) = v;
    }
    __syncthreads();
    const int tx = threadIdx.x & 15;
    const int ty = threadIdx.x >> 4;
    float acc[4][4] = {};
#pragma unroll 2
    for (int k = 0; k < HID; k += 8) {
        uint4 a[4];
#pragma unroll
        for (int i = 0; i < 4; ++i)
            a[i] = *(const uint4*)(hs + (ty + 16 * i) * HS_LD + k);
        float4 w[8];
#pragma unroll
        for (int m = 0; m < 8; ++m)
            w[m] = *(const float4*)(ws + (k + m) * HID + tx * 4);
#pragma unroll
        for (int i = 0; i < 4; ++i) {
            float h0 = bf_lo(a[i].x), h1 = bf_hi(a[i].x);
            float h2 = bf_lo(a[i].y), h3 = bf_hi(a[i].y);
            float h4 = bf_lo(a[i].z), h5 = bf_hi(a[i].z);
            float h6 = bf_lo(a[i].w), h7 = bf_hi(a[i].w);
            acc[i][0] += h0 * w[0].x + h1 * w[1].x + h2 * w[2].x + h3 * w[3].x
                       + h4 * w[4].x + h5 * w[5].x + h6 * w[6].x + h7 * w[7].x;
            acc[i][1] += h0 * w[0].y + h1 * w[1].y + h2 * w[2].y + h3 * w[3].y
                       + h4 * w[4].y + h5 * w[5].y + h6 * w[6].y + h7 * w[7].y;
            acc[i][2] += h0 * w[0].z + h1 * w[1].z + h2 * w[2].z + h3 * w[3].z
                       + h4 * w[4].z + h5 * w[5].z + h6 * w[6].z + h7 * w[7].z;
            acc[i][3] += h0 * w[0].w + h1 * w[1].w + h2 * w[2].w + h3 * w[3].w
                       + h4 * w[4].w + h5 * w[5].w + h6 * w[6].w + h7 * w[7].w;
        }
    }
#pragma unroll
    for (int i = 0; i < 4; ++i) {
        int rr = row_base + ty + 16 * i;
        if (rr < N_NODES) {
            float d = dis[rr];
            ushort4 o;
            o.x = f2bf(d * acc[i][0]);
            o.y = f2bf(d * acc[i][1]);
            o.z = f2bf(d * acc[i][2]);
            o.w = f2bf(d * acc[i][3]);
            *(ushort4*)(p + (size_t)rr * HID + tx * 4) = o;
        }
    }
}

// ---------- round-8 gather core (empirical optimum): 32/16/masked-8 loops ----------
// lane L: q = L>>3 (row slot), g = L&7 (feature octet, feats 8g..8g+7)
__device__ __forceinline__ float gather_node(const unsigned short* __restrict__ p,
                                             const int* __restrict__ adj,
                                             int c, int beg, int end, int q, int g) {
    float acc[8];
    {   // self-loop row, counted once via q==0 lanes
        uint4 s = *(const uint4*)(p + (size_t)c * HID + g * 8);
        float sm = (q == 0) ? 1.f : 0.f;
        acc[0] = sm * bf_lo(s.x); acc[1] = sm * bf_hi(s.x);
        acc[2] = sm * bf_lo(s.y); acc[3] = sm * bf_hi(s.y);
        acc[4] = sm * bf_lo(s.z); acc[5] = sm * bf_hi(s.z);
        acc[6] = sm * bf_lo(s.w); acc[7] = sm * bf_hi(s.w);
    }
    int e = beg;
    for (; e + 32 <= end; e += 32) {            // 4 row-loads in flight
        int r0 = adj[e + q];
        int r1 = adj[e + 8 + q];
        int r2 = adj[e + 16 + q];
        int r3 = adj[e + 24 + q];
        uint4 v0 = *(const uint4*)(p + (size_t)r0 * HID + g * 8);
        uint4 v1 = *(const uint4*)(p + (size_t)r1 * HID + g * 8);
        uint4 v2 = *(const uint4*)(p + (size_t)r2 * HID + g * 8);
        uint4 v3 = *(const uint4*)(p + (size_t)r3 * HID + g * 8);
        acc[0] += (bf_lo(v0.x) + bf_lo(v1.x)) + (bf_lo(v2.x) + bf_lo(v3.x));
        acc[1] += (bf_hi(v0.x) + bf_hi(v1.x)) + (bf_hi(v2.x) + bf_hi(v3.x));
        acc[2] += (bf_lo(v0.y) + bf_lo(v1.y)) + (bf_lo(v2.y) + bf_lo(v3.y));
        acc[3] += (bf_hi(v0.y) + bf_hi(v1.y)) + (bf_hi(v2.y) + bf_hi(v3.y));
        acc[4] += (bf_lo(v0.z) + bf_lo(v1.z)) + (bf_lo(v2.z) + bf_lo(v3.z));
        acc[5] += (bf_hi(v0.z) + bf_hi(v1.z)) + (bf_hi(v2.z) + bf_hi(v3.z));
        acc[6] += (bf_lo(v0.w) + bf_lo(v1.w)) + (bf_lo(v2.w) + bf_lo(v3.w));
        acc[7] += (bf_hi(v0.w) + bf_hi(v1.w)) + (bf_hi(v2.w) + bf_hi(v3.w));
    }
    for (; e + 16 <= end; e += 16) {
        int r0 = adj[e + q];
        int r1 = adj[e + 8 + q];
        uint4 v0 = *(const uint4*)(p + (size_t)r0 * HID + g * 8);
        uint4 v1 = *(const uint4*)(p + (size_t)r1 * HID + g * 8);
        acc[0] += bf_lo(v0.x) + bf_lo(v1.x); acc[1] += bf_hi(v0.x) + bf_hi(v1.x);
        acc[2] += bf_lo(v0.y) + bf_lo(v1.y); acc[3] += bf_hi(v0.y) + bf_hi(v1.y);
        acc[4] += bf_lo(v0.z) + bf_lo(v1.z); acc[5] += bf_hi(v0.z) + bf_hi(v1.z);
        acc[6] += bf_lo(v0.w) + bf_lo(v1.w); acc[7] += bf_hi(v0.w) + bf_hi(v1.w);
    }
    for (; e < end; e += 8) {                   // masked tail
        int idx = e + q;
        int r = adj[min(idx, end - 1)];
        float m = (idx < end) ? 1.f : 0.f;
        uint4 v = *(const uint4*)(p + (size_t)r * HID + g * 8);
        acc[0] = fmaf(m, bf_lo(v.x), acc[0]); acc[1] = fmaf(m, bf_hi(v.x), acc[1]);
        acc[2] = fmaf(m, bf_lo(v.y), acc[2]); acc[3] = fmaf(m, bf_hi(v.y), acc[3]);
        acc[4] = fmaf(m, bf_lo(v.z), acc[4]); acc[5] = fmaf(m, bf_hi(v.z), acc[5]);
        acc[6] = fmaf(m, bf_lo(v.w), acc[6]); acc[7] = fmaf(m, bf_hi(v.w), acc[7]);
    }
    // select-tree reduction over q bits (lane ends with feature 8g+q)
    const bool q0 = (q & 1) != 0, q1 = (q & 2) != 0, q2 = (q & 4) != 0;
    float b0 = (q0 ? acc[1] : acc[0]) + __shfl_xor(q0 ? acc[0] : acc[1], 8, 64);
    float b1 = (q0 ? acc[3] : acc[2]) + __shfl_xor(q0 ? acc[2] : acc[3], 8, 64);
    float b2 = (q0 ? acc[5] : acc[4]) + __shfl_xor(q0 ? acc[4] : acc[5], 8, 64);
    float b3 = (q0 ? acc[7] : acc[6]) + __shfl_xor(q0 ? acc[6] : acc[7], 8, 64);
    float c0 = (q1 ? b1 : b0) + __shfl_xor(q1 ? b0 : b1, 16, 64);
    float c1 = (q1 ? b3 : b2) + __shfl_xor(q1 ? b2 : b3, 16, 64);
    return (q2 ? c1 : c0) + __shfl_xor(q2 ? c0 : c1, 32, 64);
}

// ---------- gather1: hb = bf16(relu(dis[c]*(p[c]+sum p[r]) + b1)), contiguous chunks ----------
__global__ __launch_bounds__(256) void gather1_kernel(const unsigned short* __restrict__ p,
                                                      const int* __restrict__ adj,
                                                      const int* __restrict__ offs,
                                                      const float* __restrict__ dis,
                                                      const float* __restrict__ b1,
                                                      unsigned short* __restrict__ hb) {
    const int lane = threadIdx.x & 63;
    const int q = lane >> 3, g = lane & 7;
    const int gwave = (blockIdx.x * blockDim.x + threadIdx.x) >> 6;
    const int nwaves = (gridDim.x * blockDim.x) >> 6;
    const int per = (N_NODES + nwaves - 1) / nwaves;
    const int c0 = gwave * per;
    const int c1 = min(N_NODES, c0 + per);
    const float bj = b1[g * 8 + q];
    if (c0 >= c1) return;
    int beg = offs[c0];                       // carry offs[c+1] -> next beg
    for (int c = c0; c < c1; ++c) {
        const int end = offs[c + 1];
        float val = gather_node(p, adj, c, beg, end, q, g);
        hb[(size_t)c * HID + g * 8 + q] = f2bf(fmaxf(dis[c] * val + bj, 0.f));
        beg = end;
    }
}

// ---------- gather2 + mean-pool numerator (run-length atomics over sorted batch) ----------
__global__ __launch_bounds__(256) void gather2_kernel(const unsigned short* __restrict__ p,
                                                      const int* __restrict__ adj,
                                                      const int* __restrict__ offs,
                                                      const float* __restrict__ dis,
                                                      const float* __restrict__ b2,
                                                      const int* __restrict__ batch,
                                                      float* __restrict__ sums) {
    const int lane = threadIdx.x & 63;
    const int q = lane >> 3, g = lane & 7;
    const int gwave = (blockIdx.x * blockDim.x + threadIdx.x) >> 6;
    const int nwaves = (gridDim.x * blockDim.x) >> 6;
    const int per = (N_NODES + nwaves - 1) / nwaves;
    const int c0 = gwave * per;
    const int c1 = min(N_NODES, c0 + per);
    const float bj = b2[g * 8 + q];
    const int feat = g * 8 + q;
    float part = 0.f;
    int gc = -1;
    if (c0 >= c1) return;
    int beg = offs[c0];                       // carry offs[c+1] -> next beg
    for (int c = c0; c < c1; ++c) {
        const int end = offs[c + 1];
        float val = gather_node(p, adj, c, beg, end, q, g);
        float v = fmaxf(dis[c] * val + bj, 0.f);
        int gid = batch[c];                       // wave-uniform
        if (gid != gc) {
            if (gc >= 0) atomicAdd(&sums[(size_t)gc * HID + feat], part);
            part = 0.f;
            gc = gid;
        }
        part += v;
        beg = end;
    }
    if (gc >= 0) atomicAdd(&sums[(size_t)gc * HID + feat], part);
}

// ---------- final FC (counts fused via binary search on sorted batch) ----------
__global__ void fc_kernel(const float* __restrict__ sums, const int* __restrict__ batch,
                          const float* __restrict__ Wfc, const float* __restrict__ bfc,
                          float* __restrict__ out) {
    const int g = blockIdx.x;
    const int j = threadIdx.x;
    int lo = 0, hi = N_NODES;
    while (lo < hi) { int m = (lo + hi) >> 1; if (batch[m] < g) lo = m + 1; else hi = m; }
    const int l0 = lo;
    lo = 0; hi = N_NODES;
    while (lo < hi) { int m = (lo + hi) >> 1; if (batch[m] < g + 1) lo = m + 1; else hi = m; }
    float cnt = fmaxf((float)(lo - l0), 1.0f);
    float pj = sums[(size_t)g * HID + j] / cnt;
    float a0 = pj * Wfc[j * N_CLASSES + 0];
    float a1 = pj * Wfc[j * N_CLASSES + 1];
    for (int off = 32; off > 0; off >>= 1) {
        a0 += __shfl_down(a0, off, 64);
        a1 += __shfl_down(a1, off, 64);
    }
    if (j == 0) {
        out[g * N_CLASSES + 0] = a0 + bfc[0];
        out[g * N_CLASSES + 1] = a1 + bfc[1];
    }
}

extern "C" void kernel_launch(void* const* d_in, const int* in_sizes, int n_in,
                              void* d_out, int out_size, void* d_ws, size_t ws_size,
                              hipStream_t stream) {
    const float* x     = (const float*)d_in[0];
    const int*   ei    = (const int*)d_in[1];   // [2,E]: row=ei[0:E], col=ei[E:2E]
    const int*   batch = (const int*)d_in[2];
    const float* W1    = (const float*)d_in[3];
    const float* b1    = (const float*)d_in[4];
    const float* W2    = (const float*)d_in[5];
    const float* b2    = (const float*)d_in[6];
    const float* Wfc   = (const float*)d_in[7];
    const float* bfc   = (const float*)d_in[8];
    float* out = (float*)d_out;

    char* ws = (char*)d_ws;
    size_t off = 0;
    auto alloc = [&](size_t bytes) -> void* {
        void* pp = ws + off;
        off += (bytes + 255) & ~(size_t)255;
        return pp;
    };
    // gcur and sums adjacent -> single memset covers both
    int*   gcur   = (int*)alloc((size_t)NB * 4);                      // 1.6 KB (pads to 1792B)
    float* sums   = (float*)alloc((size_t)N_GRAPHS * HID * 4);        // 128 KB
    int*   offs   = (int*)alloc((size_t)(N_NODES + 1) * 4);
    float* dis    = (float*)alloc((size_t)N_NODES * 4);
    int*   pairs  = (int*)alloc((size_t)NB * CAP2 * 4);               // 14.0 MB
    int*   adj    = (int*)alloc((size_t)N_EDGES * 4);
    float* praw   = (float*)alloc((size_t)N_NODES * HID * 4);         // 25.6 MB f32
    unsigned short* p  = (unsigned short*)alloc((size_t)N_NODES * HID * 2);
    unsigned short* hb = (unsigned short*)alloc((size_t)N_NODES * HID * 2);

    hipMemsetAsync(gcur, 0, (size_t)((char*)(sums + N_GRAPHS * HID) - (char*)gcur), stream);

    fused_pre<<<SCAT_BLOCKS + MM1_BLOCKS, 256, 0, stream>>>(ei, gcur, pairs, x, W1, praw);
    csrX<<<NB, 512, 0, stream>>>(pairs, gcur, praw, p, adj, offs, dis);
    gather1_kernel<<<2048, 256, 0, stream>>>(p, adj, offs, dis, b1, hb);
    mm2_kernel<<<(N_NODES + 63) / 64, 256, 0, stream>>>(hb, W2, dis, p);
    gather2_kernel<<<2048, 256, 0, stream>>>(p, adj, offs, dis, b2, batch, sums);
    fc_kernel<<<N_GRAPHS, 64, 0, stream>>>(sums, batch, Wfc, bfc, out);
}